// Round 16
// baseline (345.235 us; speedup 1.0000x reference)
//
#include <hip/hip_runtime.h>

#define P_PIX 22500
#define HB 61
#define HSP 22           // pixel splits (48*22=1056 blocks); 256-px chunks
#define PPB 1024
#define NCHK 4

typedef float f32x4 __attribute__((ext_vector_type(4)));
typedef _Float16 f16x8 __attribute__((ext_vector_type(8)));
typedef _Float16 f16x4 __attribute__((ext_vector_type(4)));

// ---------------------------------------------------------------------------
// MFMA RGB-uv soft histogram.  grid (48, HSP), block 256.
// 256-px chunks: phase 1 uses ALL threads (was 128/256) and barrier count
// halves (3 per 256 px, was 6).  Register A fragments, B table in LDS (32KB).
// Factored Gaussian (r7), __expf (r10), no atomics (r11).
// ---------------------------------------------------------------------------
__global__ __launch_bounds__(256) void hist_mfma(
    const float* __restrict__ img, const float* __restrict__ su,
    const float* __restrict__ sv, const float* __restrict__ cw,
    const float* __restrict__ msc, float* __restrict__ hpart)
{
    const int bc = blockIdx.x;
    const int b = bc / 3, c = bc % 3;
    const int split = blockIdx.y;
    const int tid  = threadIdx.x;
    const int wv   = tid >> 6;
    const int lane = tid & 63;
    const int quad = lane >> 4;
    const int mr   = lane & 15;

    __shared__ __align__(16) _Float16 B_lds[16384];  // [pg(32)][vbin(64)][j(8)]
    __shared__ float suu[256], svv[256], sww[256];

    const float sig_u = su[c], sig_v = sv[c];
    const float inv_su2 = 1.f / (sig_u * sig_u);
    const float inv_sv2 = 1.f / (sig_v * sig_v);
    const float cwc = cw[c];
    const float ubin_b = -3.f + 0.1f * (float)lane;
    const float ubin_a = -3.f + 0.1f * (float)(wv * 16 + mr);

    const bool hasM = (msc != nullptr);
    float m00=0,m01=0,m02=0,m10=0,m11=0,m12=0,m20=0,m21=0,m22=0;
    if (hasM) {
        const float* mp = msc + b * 9;
        m00=mp[0]; m01=mp[1]; m02=mp[2];
        m10=mp[3]; m11=mp[4]; m12=mp[5];
        m20=mp[6]; m21=mp[7]; m22=mp[8];
    }

    const int p0   = split * PPB;
    const int pend = min(p0 + PPB, P_PIX);

    f32x4 acc[4];
#pragma unroll
    for (int nt = 0; nt < 4; ++nt) acc[nt] = (f32x4){0.f, 0.f, 0.f, 0.f};

    for (int chunk = 0; chunk < NCHK; ++chunk) {
        __syncthreads();
        // ---- phase 1: (u, v, weight) for 256 pixels, all threads ----
        {
            int px = p0 + chunk * 256 + tid;
            float u = 0.f, v = 0.f, wgt = 0.f;
            if (px < pend) {
                const float* ip = img + (size_t)b * 3 * P_PIX + px;
                float r = ip[0], g = ip[P_PIX], bl = ip[2 * P_PIX];
                if (hasM) {
                    float r2 = m00 * r + m01 * g + m02 * bl;
                    float g2 = m10 * r + m11 * g + m12 * bl;
                    float b2 = m20 * r + m21 * g + m22 * bl;
                    r = r2; g = g2; bl = b2;
                }
                r  = fminf(fmaxf(r, 0.f), 1.f);
                g  = fminf(fmaxf(g, 0.f), 1.f);
                bl = fminf(fmaxf(bl, 0.f), 1.f);
                float Iy = sqrtf(r * r + g * g + bl * bl);
                float lr = __logf(r + 1e-6f);
                float lg = __logf(g + 1e-6f);
                float lb = __logf(bl + 1e-6f);
                if (c == 0)      { u = lr - lg; v = lr - lb; }
                else if (c == 1) { u = lg - lr; v = lg - lb; }
                else             { u = lb - lr; v = lb - lg; }
                wgt = Iy * cwc;
            }
            suu[tid] = u; svv[tid] = v; sww[tid] = wgt;
        }
        __syncthreads();
        // ---- phase 2a: B table (kv) into LDS, 32 pixel-groups ----
#pragma unroll
        for (int r = 0; r < 8; ++r) {
            int pg = wv + 4 * r;
            f32x4 v0 = *(const f32x4*)&svv[pg * 8];
            f32x4 v1 = *(const f32x4*)&svv[pg * 8 + 4];
            f16x8 bv;
#pragma unroll
            for (int j = 0; j < 4; ++j) {
                float dv = v0[j] - ubin_b;
                bv[j] = (_Float16)__expf(-dv * dv * inv_sv2);
                float dv1 = v1[j] - ubin_b;
                bv[4 + j] = (_Float16)__expf(-dv1 * dv1 * inv_sv2);
            }
            *(f16x8*)&B_lds[(pg * 64 + lane) * 8] = bv;
        }
        // ---- phase 2b: A fragments (ku*w) into registers ----
        f16x8 af[8];
#pragma unroll
        for (int kk = 0; kk < 8; ++kk) {
            int pxg = kk * 4 + quad;
            f32x4 u0 = *(const f32x4*)&suu[pxg * 8];
            f32x4 u1 = *(const f32x4*)&suu[pxg * 8 + 4];
            f32x4 w0 = *(const f32x4*)&sww[pxg * 8];
            f32x4 w1 = *(const f32x4*)&sww[pxg * 8 + 4];
#pragma unroll
            for (int j = 0; j < 4; ++j) {
                float du = u0[j] - ubin_a;
                af[kk][j] = (_Float16)(__expf(-du * du * inv_su2) * w0[j]);
                float du1 = u1[j] - ubin_a;
                af[kk][4 + j] = (_Float16)(__expf(-du1 * du1 * inv_su2) * w1[j]);
            }
        }
        __syncthreads();
        // ---- phase 3: MFMA ----
#pragma unroll
        for (int kk = 0; kk < 8; ++kk) {
            int pgq = kk * 4 + quad;
#pragma unroll
            for (int nt = 0; nt < 4; ++nt) {
                f16x8 bvv = *(const f16x8*)&B_lds[(pgq * 64 + nt * 16 + mr) * 8];
                acc[nt] = __builtin_amdgcn_mfma_f32_16x16x32_f16(af[kk], bvv, acc[nt], 0, 0, 0);
            }
        }
    }

    float* hp = hpart + ((size_t)bc * HSP + split) * 4096;
#pragma unroll
    for (int nt = 0; nt < 4; ++nt) {
        int v = nt * 16 + mr;
#pragma unroll
        for (int r = 0; r < 4; ++r) {
            int u = wv * 16 + quad * 4 + r;
            hp[u * 64 + v] = acc[nt][r];
        }
    }
}

// ---------------------------------------------------------------------------
// Sum HSP slabs -> hist; per-(b,c) total -> hsum3.
// ---------------------------------------------------------------------------
__global__ __launch_bounds__(256) void reduce_hist(
    const float* __restrict__ hpart, float* __restrict__ hist,
    float* __restrict__ hsum3)
{
    const int bc = blockIdx.x;
    const int part = blockIdx.y;
    const int tid = threadIdx.x;
    const float* base = hpart + (size_t)bc * HSP * 4096;
    float lsum = 0.f;
#pragma unroll
    for (int t = 0; t < 4; ++t) {
        int idx = part * 1024 + t * 256 + tid;
        int u = idx >> 6, v = idx & 63;
        float s = 0.f;
        for (int sp = 0; sp < HSP; ++sp) s += base[sp * 4096 + idx];
        if (u < HB && v < HB) {
            hist[(size_t)bc * (HB * HB) + u * HB + v] = s;
            lsum += s;
        }
    }
    __shared__ float red[4];
    for (int off = 32; off; off >>= 1) lsum += __shfl_down(lsum, off, 64);
    if ((tid & 63) == 0) red[tid >> 6] = lsum;
    __syncthreads();
    if (tid == 0) atomicAdd(&hsum3[bc], red[0] + red[1] + red[2] + red[3]);
}

// ---------------------------------------------------------------------------
// conv1 implicit-GEMM MFMA, NHWC output, M-tile 64 (r15, verified).
// ---------------------------------------------------------------------------
__global__ __launch_bounds__(256) void conv1_mfma(
    const float* __restrict__ hist, const float* __restrict__ hsum3,
    const _Float16* __restrict__ w1h, const float* __restrict__ bias,
    _Float16* __restrict__ out)
{
    const int b    = blockIdx.x;
    const int m0   = blockIdx.y * 64;
    const int tid  = threadIdx.x;
    const int wv   = tid >> 6;
    const int lane = tid & 63;
    const int quad = lane >> 4;
    const int mr   = lane & 15;

    __shared__ __align__(16) _Float16 A_lds[64 * 96];

    const float sc = 1.f / (hsum3[b * 3] + hsum3[b * 3 + 1] + hsum3[b * 3 + 2] + 1e-6f);
    const float* inb = hist + (size_t)b * 3 * 3721;

    for (int slot = tid; slot < 768; slot += 256) {
        int m  = slot & 63;
        int kg = slot >> 6;
        int mg = m0 + m;
        bool mok = (mg < 841);
        int oh = mok ? mg / 29 : 0;
        int ow = mok ? mg % 29 : 0;
        const float* pbase = inb + (oh * 2) * 61 + (ow * 2);
        f16x8 av;
#pragma unroll
        for (int j = 0; j < 8; ++j) {
            int k = kg * 8 + j;
            float x = 0.f;
            if (mok && k < 75) {
                int ci = k / 25, r = k % 25;
                int kh = r / 5, kw = r % 5;
                x = pbase[ci * 3721 + kh * 61 + kw] * sc;
            }
            av[j] = (_Float16)x;
        }
        *(f16x8*)&A_lds[(kg * 64 + m) * 8] = av;
    }
    __syncthreads();

    f16x8 wf[3][2];
#pragma unroll
    for (int ks = 0; ks < 3; ++ks)
#pragma unroll
        for (int nt = 0; nt < 2; ++nt) {
            int co = (wv * 2 + nt) * 16 + mr;
            wf[ks][nt] = *(const f16x8*)&w1h[co * 96 + ks * 32 + quad * 8];
        }

    f32x4 acc[4][2];
#pragma unroll
    for (int mt = 0; mt < 4; ++mt)
#pragma unroll
        for (int nt = 0; nt < 2; ++nt) acc[mt][nt] = (f32x4){0.f, 0.f, 0.f, 0.f};

#pragma unroll
    for (int ks = 0; ks < 3; ++ks)
#pragma unroll
        for (int mt = 0; mt < 4; ++mt) {
            f16x8 bv = *(const f16x8*)&A_lds[((ks * 4 + quad) * 64 + mt * 16 + mr) * 8];
#pragma unroll
            for (int nt = 0; nt < 2; ++nt)
                acc[mt][nt] = __builtin_amdgcn_mfma_f32_16x16x32_f16(bv, wf[ks][nt], acc[mt][nt], 0, 0, 0);
        }

#pragma unroll
    for (int mt = 0; mt < 4; ++mt) {
#pragma unroll
        for (int r = 0; r < 4; ++r) {
            int sp = m0 + mt * 16 + quad * 4 + r;
            if (sp >= 841) continue;
#pragma unroll
            for (int nt = 0; nt < 2; ++nt) {
                int co = (wv * 2 + nt) * 16 + mr;
                float y = acc[mt][nt][r] + bias[co];
                out[((size_t)b * 841 + sp) * 128 + co] = (_Float16)fmaxf(y, 0.f);
            }
        }
    }
}

// ---------------------------------------------------------------------------
// conv2/conv3 implicit-GEMM MFMA, NHWC in/out (r15, verified).
// ---------------------------------------------------------------------------
template<int CIN, int COUT, int Kk, int S, int IN, int OUT,
         int NPB, int KSPL, int KCH>
__global__ __launch_bounds__(256) void conv_mfma(
    const _Float16* __restrict__ in_h,
    const _Float16* __restrict__ w_h,
    float* __restrict__ out)             // [KSPL][B][OSZ][COUT]
{
    constexpr int KK   = Kk * Kk;
    constexpr int OSZ  = OUT * OUT;
    constexpr int MT   = (OSZ + 15) / 16;
    constexpr int MP   = MT * 16;
    constexpr int KTOT = CIN * KK;
    constexpr int KC   = KTOT / KSPL;
    constexpr int NCHUNK = KC / KCH;
    constexpr int NT   = NPB / 64;
    constexpr int KSN  = KCH / 32;
    constexpr int SLOTS = MP * (KCH / 8);

    const int b   = blockIdx.x;
    const int co0 = blockIdx.y * NPB;
    const int k00 = blockIdx.z * KC;
    const int tid  = threadIdx.x;
    const int wv   = tid >> 6;
    const int lane = tid & 63;
    const int quad = lane >> 4;
    const int mr   = lane & 15;

    __shared__ __align__(16) _Float16 A_lds[MP * KCH];

    const _Float16* inb = in_h + (size_t)b * (IN * IN) * CIN;
    float* outp = out + (size_t)blockIdx.z * gridDim.x * OSZ * COUT;

    f32x4 acc[MT][NT];
#pragma unroll
    for (int mt = 0; mt < MT; ++mt)
#pragma unroll
        for (int nt = 0; nt < NT; ++nt) acc[mt][nt] = (f32x4){0.f, 0.f, 0.f, 0.f};

    for (int ch = 0; ch < NCHUNK; ++ch) {
        const int k0 = k00 + ch * KCH;
        __syncthreads();
        for (int slot = tid; slot < SLOTS; slot += 256) {
            int m  = slot % MP;
            int kg = slot / MP;
            bool mok = (m < OSZ);
            int oh = mok ? m / OUT : 0;
            int ow = mok ? m % OUT : 0;
            int kbase = k0 + kg * 8;
            int khkw = kbase / CIN;
            int ci0  = kbase % CIN;
            int kh = khkw / Kk, kw = khkw % Kk;
            f16x8 av = (f16x8)(_Float16)0.f;
            if (mok)
                av = *(const f16x8*)&inb[((size_t)((oh * S + kh) * IN + (ow * S + kw))) * CIN + ci0];
            *(f16x8*)&A_lds[(kg * MP + m) * 8] = av;
        }
        __syncthreads();
        f16x8 wf[KSN][NT];
#pragma unroll
        for (int ks = 0; ks < KSN; ++ks)
#pragma unroll
            for (int nt = 0; nt < NT; ++nt) {
                int co = co0 + (wv * NT + nt) * 16 + mr;
                wf[ks][nt] = *(const f16x8*)&w_h[(size_t)co * KTOT + k0 + ks * 32 + quad * 8];
            }
#pragma unroll
        for (int ks = 0; ks < KSN; ++ks) {
#pragma unroll
            for (int mt = 0; mt < MT; ++mt) {
                f16x8 bv = *(const f16x8*)&A_lds[((ks * 4 + quad) * MP + mt * 16 + mr) * 8];
#pragma unroll
                for (int nt = 0; nt < NT; ++nt)
                    acc[mt][nt] = __builtin_amdgcn_mfma_f32_16x16x32_f16(bv, wf[ks][nt], acc[mt][nt], 0, 0, 0);
            }
        }
    }

#pragma unroll
    for (int mt = 0; mt < MT; ++mt) {
#pragma unroll
        for (int r = 0; r < 4; ++r) {
            int sp = mt * 16 + quad * 4 + r;
            if (sp >= OSZ) continue;
#pragma unroll
            for (int nt = 0; nt < NT; ++nt) {
                int co = co0 + (wv * NT + nt) * 16 + mr;
                outp[((size_t)b * OSZ + sp) * COUT + co] = acc[mt][nt][r];
            }
        }
    }
}

// ---------------------------------------------------------------------------
// float4 split-K reduce + bias + ReLU -> f16 (NHWC: co = 4i % cout).
// ---------------------------------------------------------------------------
__global__ __launch_bounds__(256) void reduce_bias_relu_f16(
    const float* __restrict__ p, const float* __restrict__ bias,
    _Float16* __restrict__ out, int cout, int total4, int kspl, int total)
{
    for (int i4 = blockIdx.x * 256 + threadIdx.x; i4 < total4; i4 += gridDim.x * 256) {
        f32x4 s = (f32x4){0.f, 0.f, 0.f, 0.f};
        for (int ks = 0; ks < kspl; ++ks)
            s += *(const f32x4*)&p[(size_t)ks * total + i4 * 4];
        f32x4 bb = *(const f32x4*)&bias[(i4 * 4) % cout];
        f16x4 o;
#pragma unroll
        for (int j = 0; j < 4; ++j) o[j] = (_Float16)fmaxf(s[j] + bb[j], 0.f);
        *(f16x4*)&out[(size_t)i4 * 4] = o;
    }
}

// ---------------------------------------------------------------------------
// fc as split-K MFMA (r14, verified).
// ---------------------------------------------------------------------------
__global__ __launch_bounds__(256) void fc_mfma(
    const _Float16* __restrict__ z, const _Float16* __restrict__ fcw,
    float* __restrict__ out, int NO)
{
    const int tid  = threadIdx.x;
    const int wv   = tid >> 6;
    const int lane = tid & 63;
    const int quad = lane >> 4;
    const int mr   = lane & 15;
    const int kw0  = blockIdx.x * 512 + wv * 128;

    __shared__ float sred[1024];

    f32x4 acc = (f32x4){0.f, 0.f, 0.f, 0.f};
    const bool bok = (mr < NO);
#pragma unroll
    for (int ks = 0; ks < 4; ++ks) {
        int kk = kw0 + ks * 32 + quad * 8;
        f16x8 av = *(const f16x8*)&z[(size_t)mr * 86528 + kk];
        f16x8 bw = (f16x8)(_Float16)0.f;
        if (bok) bw = *(const f16x8*)&fcw[(size_t)mr * 86528 + kk];
        acc = __builtin_amdgcn_mfma_f32_16x16x32_f16(av, bw, acc, 0, 0, 0);
    }
#pragma unroll
    for (int r = 0; r < 4; ++r)
        sred[wv * 256 + (quad * 4 + r) * 16 + mr] = acc[r];
    __syncthreads();
    if (tid < 256) {
        float s = sred[tid] + sred[256 + tid] + sred[512 + tid] + sred[768 + tid];
        int o = tid & 15, b = tid >> 4;
        if (o < NO) atomicAdd(&out[b * NO + o], s);
    }
}

// ---------------------------------------------------------------------------
// ONE weight-prep kernel (r15, verified).
// ---------------------------------------------------------------------------
__global__ __launch_bounds__(256) void prep_weights(
    const float* __restrict__ w1s, const float* __restrict__ w1i,
    const float* __restrict__ w2s, const float* __restrict__ w3s,
    const float* __restrict__ w2i, const float* __restrict__ w3i,
    const float* __restrict__ fcs, const float* __restrict__ fci,
    _Float16* __restrict__ w1h, _Float16* __restrict__ w23,
    _Float16* __restrict__ fch, float* __restrict__ zp)
{
    const int R0 = 384;
    const int R1 = 24576;
    const int N2 = 294912, N3 = 524288;
    const int R2 = 2 * (N2 + N3);
    const int K = 86528;
    const int R3 = 12 * K;
    const int T = R0 + R1 + R2 + R3;
    for (int i = blockIdx.x * 256 + threadIdx.x; i < T; i += gridDim.x * 256) {
        if (i < R0) {
            zp[i] = 0.f;
        } else if (i < R0 + R1) {
            int r0 = i - R0;
            int br = r0 / 12288, r = r0 % 12288;
            int co = r / 96, k = r % 96;
            const float* s = br ? w1i : w1s;
            w1h[r0] = (k < 75) ? (_Float16)s[co * 75 + k] : (_Float16)0.f;
        } else if (i < R0 + R1 + R2) {
            int j = i - R0 - R1;
            int out_idx = j;
            const float* s; int CK, KKn;
            if (j < N2)                { s = w2s; CK = 1152; KKn = 9; }
            else if (j < N2 + N3)      { s = w3s; j -= N2; CK = 1024; KKn = 4; }
            else if (j < 2 * N2 + N3)  { s = w2i; j -= N2 + N3; CK = 1152; KKn = 9; }
            else                       { s = w3i; j -= 2 * N2 + N3; CK = 1024; KKn = 4; }
            int co = j / CK, rem = j % CK;
            int ci = rem % (CK / KKn), khkw = rem / (CK / KKn);
            w23[out_idx] = (_Float16)s[co * CK + ci * KKn + khkw];
        } else {
            int j = i - R0 - R1 - R2;
            int o = j / K, rem = j % K;
            int sp = rem / 512, co = rem % 512;
            const float* s = (o < 9) ? (fcs + o * K) : (fci + (o - 9) * K);
            fch[j] = (_Float16)s[co * 169 + sp];
        }
    }
}

// ---------------------------------------------------------------------------
// m = reshape(|h|,3,3)^T; n = max L1 row norm + 1e-4; msc = m / n.
// ---------------------------------------------------------------------------
__global__ void build_m(const float* __restrict__ h, float* __restrict__ msc)
{
    int b = threadIdx.x;
    if (b < 16) {
        float m[9];
#pragma unroll
        for (int i = 0; i < 3; ++i)
#pragma unroll
            for (int j = 0; j < 3; ++j) m[i * 3 + j] = fabsf(h[b * 9 + j * 3 + i]);
        float n = 0.f;
#pragma unroll
        for (int i = 0; i < 3; ++i) {
            float r = m[i * 3] + m[i * 3 + 1] + m[i * 3 + 2];
            n = fmaxf(n, r);
        }
        n += 1e-4f;
        float inv = 1.f / n;
#pragma unroll
        for (int k = 0; k < 9; ++k) msc[b * 9 + k] = m[k] * inv;
    }
}

// ---------------------------------------------------------------------------
// est[b] = inv(msc[b]) @ |ill[b]|
// ---------------------------------------------------------------------------
__global__ void final_est(const float* __restrict__ msc, const float* __restrict__ ill,
                          float* __restrict__ out)
{
    int bidx = threadIdx.x;
    if (bidx < 16) {
        const float* m = msc + bidx * 9;
        float a = m[0], b = m[1], c = m[2];
        float d = m[3], e = m[4], f = m[5];
        float g = m[6], h = m[7], i = m[8];
        float A = e * i - f * h, B = f * g - d * i, C = d * h - e * g;
        float D = c * h - b * i, E = a * i - c * g, F = b * g - a * h;
        float G = b * f - c * e, H = c * d - a * f, I = a * e - b * d;
        float det = a * A + b * B + c * C;
        float inv_det = 1.f / det;
        float x0 = fabsf(ill[bidx * 3 + 0]);
        float x1 = fabsf(ill[bidx * 3 + 1]);
        float x2 = fabsf(ill[bidx * 3 + 2]);
        out[bidx * 3 + 0] = (A * x0 + D * x1 + G * x2) * inv_det;
        out[bidx * 3 + 1] = (B * x0 + E * x1 + H * x2) * inv_det;
        out[bidx * 3 + 2] = (C * x0 + F * x1 + I * x2) * inv_det;
    }
}

extern "C" void kernel_launch(void* const* d_in, const int* in_sizes, int n_in,
                              void* d_out, int out_size, void* d_ws, size_t ws_size,
                              hipStream_t stream)
{
    (void)in_sizes; (void)n_in; (void)out_size; (void)ws_size;
    const float* image = (const float*)d_in[0];
    const float* su_s  = (const float*)d_in[1];
    const float* sv_s  = (const float*)d_in[2];
    const float* c_s   = (const float*)d_in[3];
    const float* w1_s  = (const float*)d_in[4];
    const float* b1_s  = (const float*)d_in[5];
    const float* w2_s  = (const float*)d_in[6];
    const float* b2_s  = (const float*)d_in[7];
    const float* w3_s  = (const float*)d_in[8];
    const float* b3_s  = (const float*)d_in[9];
    const float* fc_s  = (const float*)d_in[10];
    const float* su_i  = (const float*)d_in[11];
    const float* sv_i  = (const float*)d_in[12];
    const float* c_i   = (const float*)d_in[13];
    const float* w1_i  = (const float*)d_in[14];
    const float* b1_i  = (const float*)d_in[15];
    const float* w2_i  = (const float*)d_in[16];
    const float* b2_i  = (const float*)d_in[17];
    const float* w3_i  = (const float*)d_in[18];
    const float* b3_i  = (const float*)d_in[19];
    const float* fc_i  = (const float*)d_in[20];

    // ---- workspace: cumulative pointer arithmetic ONLY; hpart/p2/p3 union
    float* W      = (float*)d_ws;
    float* hist   = W;                        // 178608 f
    float* hd     = hist + 178608;            // 144 (zeroed in prep)
    float* hd2    = hd + 144;                 // 144
    float* hsum3a = hd2 + 144;                // 48
    float* hsum3b = hsum3a + 48;              // 48
    float* msc    = hsum3b + 48;              // 144
    float* U      = msc + 144;                // union: max(hpart 48*22*4096=4325376,
                                              //   p2 9633792, p3 11075584)
    float* hpart  = U;
    float* p2     = U;
    float* p3     = U;
    _Float16* o1h   = (_Float16*)(U + 11075584);
    _Float16* o2h   = o1h   + 1722368;
    _Float16* o3h   = o2h   + 802816;
    _Float16* fch   = o3h   + 1384448;
    _Float16* w2h_s = fch   + 1038336;
    _Float16* w3h_s = w2h_s + 294912;
    _Float16* w2h_i = w3h_s + 524288;
    _Float16* w3h_i = w2h_i + 294912;
    _Float16* w1h_s = w3h_i + 524288;
    _Float16* w1h_i = w1h_s + 12288;

    const int O2_TOT = 16 * 196 * 256;
    const int O3_TOT = 16 * 169 * 512;
    const int FCK = 86528;

    prep_weights<<<1024, 256, 0, stream>>>(w1_s, w1_i, w2_s, w3_s, w2_i, w3_i,
                                           fc_s, fc_i, w1h_s, w2h_s, fch, hd);

    // ================= sensor branch =================
    hist_mfma<<<dim3(48, HSP), 256, 0, stream>>>(image, su_s, sv_s, c_s, nullptr, hpart);
    reduce_hist<<<dim3(48, 4), 256, 0, stream>>>(hpart, hist, hsum3a);
    conv1_mfma<<<dim3(16, 14), 256, 0, stream>>>(hist, hsum3a, w1h_s, b1_s, o1h);
    conv_mfma<128, 256, 3, 2, 29, 14, 128, 12, 96><<<dim3(16, 2, 12), 256, 0, stream>>>(o1h, w2h_s, p2);
    reduce_bias_relu_f16<<<784, 256, 0, stream>>>(p2, b2_s, o2h, 256, O2_TOT / 4, 12, O2_TOT);
    conv_mfma<256, 512, 2, 1, 14, 13, 128, 8, 64><<<dim3(16, 4, 8), 256, 0, stream>>>(o2h, w3h_s, p3);
    reduce_bias_relu_f16<<<1024, 256, 0, stream>>>(p3, b3_s, o3h, 512, O3_TOT / 4, 8, O3_TOT);
    fc_mfma<<<169, 256, 0, stream>>>(o3h, fch, hd, 9);
    build_m<<<1, 64, 0, stream>>>(hd, msc);

    // ================= illuminant branch =================
    hist_mfma<<<dim3(48, HSP), 256, 0, stream>>>(image, su_i, sv_i, c_i, msc, hpart);
    reduce_hist<<<dim3(48, 4), 256, 0, stream>>>(hpart, hist, hsum3b);
    conv1_mfma<<<dim3(16, 14), 256, 0, stream>>>(hist, hsum3b, w1h_i, b1_i, o1h);
    conv_mfma<128, 256, 3, 2, 29, 14, 128, 12, 96><<<dim3(16, 2, 12), 256, 0, stream>>>(o1h, w2h_i, p2);
    reduce_bias_relu_f16<<<784, 256, 0, stream>>>(p2, b2_i, o2h, 256, O2_TOT / 4, 12, O2_TOT);
    conv_mfma<256, 512, 2, 1, 14, 13, 128, 8, 64><<<dim3(16, 4, 8), 256, 0, stream>>>(o2h, w3h_i, p3);
    reduce_bias_relu_f16<<<1024, 256, 0, stream>>>(p3, b3_i, o3h, 512, O3_TOT / 4, 8, O3_TOT);
    fc_mfma<<<169, 256, 0, stream>>>(o3h, fch + 9 * FCK, hd2, 3);
    final_est<<<1, 64, 0, stream>>>(msc, hd2, (float*)d_out);
}

// Round 17
// 340.222 us; speedup vs baseline: 1.0147x; 1.0147x over previous
//
#include <hip/hip_runtime.h>

#define P_PIX 22500
#define HB 61
#define HSP 21
#define PPB 1152
#define NCHK 9

typedef float f32x4 __attribute__((ext_vector_type(4)));
typedef _Float16 f16x8 __attribute__((ext_vector_type(8)));
typedef _Float16 f16x4 __attribute__((ext_vector_type(4)));

// ---------------------------------------------------------------------------
// MFMA RGB-uv soft histogram (r15 config -- measured local optimum 49.5us).
// 128-px chunks, HSP=21, register-A fragments, B table in LDS.
// r13 (HSP=28) and r16 (256-px chunks) both regressed this kernel.
// ---------------------------------------------------------------------------
__global__ __launch_bounds__(256) void hist_mfma(
    const float* __restrict__ img, const float* __restrict__ su,
    const float* __restrict__ sv, const float* __restrict__ cw,
    const float* __restrict__ msc, float* __restrict__ hpart)
{
    const int bc = blockIdx.x;
    const int b = bc / 3, c = bc % 3;
    const int split = blockIdx.y;
    const int tid  = threadIdx.x;
    const int wv   = tid >> 6;
    const int lane = tid & 63;
    const int quad = lane >> 4;
    const int mr   = lane & 15;

    __shared__ __align__(16) _Float16 B_lds[8192];
    __shared__ float suu[128], svv[128], sww[128];

    const float sig_u = su[c], sig_v = sv[c];
    const float inv_su2 = 1.f / (sig_u * sig_u);
    const float inv_sv2 = 1.f / (sig_v * sig_v);
    const float cwc = cw[c];
    const float ubin_b = -3.f + 0.1f * (float)lane;
    const float ubin_a = -3.f + 0.1f * (float)(wv * 16 + mr);

    const bool hasM = (msc != nullptr);
    float m00=0,m01=0,m02=0,m10=0,m11=0,m12=0,m20=0,m21=0,m22=0;
    if (hasM) {
        const float* mp = msc + b * 9;
        m00=mp[0]; m01=mp[1]; m02=mp[2];
        m10=mp[3]; m11=mp[4]; m12=mp[5];
        m20=mp[6]; m21=mp[7]; m22=mp[8];
    }

    const int p0   = split * PPB;
    const int pend = min(p0 + PPB, P_PIX);

    f32x4 acc[4];
#pragma unroll
    for (int nt = 0; nt < 4; ++nt) acc[nt] = (f32x4){0.f, 0.f, 0.f, 0.f};

    for (int chunk = 0; chunk < NCHK; ++chunk) {
        __syncthreads();
        if (tid < 128) {
            int px = p0 + chunk * 128 + tid;
            float u = 0.f, v = 0.f, wgt = 0.f;
            if (px < pend) {
                const float* ip = img + (size_t)b * 3 * P_PIX + px;
                float r = ip[0], g = ip[P_PIX], bl = ip[2 * P_PIX];
                if (hasM) {
                    float r2 = m00 * r + m01 * g + m02 * bl;
                    float g2 = m10 * r + m11 * g + m12 * bl;
                    float b2 = m20 * r + m21 * g + m22 * bl;
                    r = r2; g = g2; bl = b2;
                }
                r  = fminf(fmaxf(r, 0.f), 1.f);
                g  = fminf(fmaxf(g, 0.f), 1.f);
                bl = fminf(fmaxf(bl, 0.f), 1.f);
                float Iy = sqrtf(r * r + g * g + bl * bl);
                float lr = __logf(r + 1e-6f);
                float lg = __logf(g + 1e-6f);
                float lb = __logf(bl + 1e-6f);
                if (c == 0)      { u = lr - lg; v = lr - lb; }
                else if (c == 1) { u = lg - lr; v = lg - lb; }
                else             { u = lb - lr; v = lb - lg; }
                wgt = Iy * cwc;
            }
            suu[tid] = u; svv[tid] = v; sww[tid] = wgt;
        }
        __syncthreads();
#pragma unroll
        for (int r = 0; r < 4; ++r) {
            int pg = wv + 4 * r;
            f32x4 v0 = *(const f32x4*)&svv[pg * 8];
            f32x4 v1 = *(const f32x4*)&svv[pg * 8 + 4];
            f16x8 bv;
#pragma unroll
            for (int j = 0; j < 4; ++j) {
                float dv = v0[j] - ubin_b;
                bv[j] = (_Float16)__expf(-dv * dv * inv_sv2);
                float dv1 = v1[j] - ubin_b;
                bv[4 + j] = (_Float16)__expf(-dv1 * dv1 * inv_sv2);
            }
            *(f16x8*)&B_lds[(pg * 64 + lane) * 8] = bv;
        }
        f16x8 af[4];
#pragma unroll
        for (int kk = 0; kk < 4; ++kk) {
            int pxg = kk * 4 + quad;
            f32x4 u0 = *(const f32x4*)&suu[pxg * 8];
            f32x4 u1 = *(const f32x4*)&suu[pxg * 8 + 4];
            f32x4 w0 = *(const f32x4*)&sww[pxg * 8];
            f32x4 w1 = *(const f32x4*)&sww[pxg * 8 + 4];
#pragma unroll
            for (int j = 0; j < 4; ++j) {
                float du = u0[j] - ubin_a;
                af[kk][j] = (_Float16)(__expf(-du * du * inv_su2) * w0[j]);
                float du1 = u1[j] - ubin_a;
                af[kk][4 + j] = (_Float16)(__expf(-du1 * du1 * inv_su2) * w1[j]);
            }
        }
        __syncthreads();
#pragma unroll
        for (int kk = 0; kk < 4; ++kk) {
            int pgq = kk * 4 + quad;
#pragma unroll
            for (int nt = 0; nt < 4; ++nt) {
                f16x8 bvv = *(const f16x8*)&B_lds[(pgq * 64 + nt * 16 + mr) * 8];
                acc[nt] = __builtin_amdgcn_mfma_f32_16x16x32_f16(af[kk], bvv, acc[nt], 0, 0, 0);
            }
        }
    }

    float* hp = hpart + ((size_t)bc * HSP + split) * 4096;
#pragma unroll
    for (int nt = 0; nt < 4; ++nt) {
        int v = nt * 16 + mr;
#pragma unroll
        for (int r = 0; r < 4; ++r) {
            int u = wv * 16 + quad * 4 + r;
            hp[u * 64 + v] = acc[nt][r];
        }
    }
}

// ---------------------------------------------------------------------------
// Sum HSP slabs -> hist; per-(b,c) total -> hsum3.
// ---------------------------------------------------------------------------
__global__ __launch_bounds__(256) void reduce_hist(
    const float* __restrict__ hpart, float* __restrict__ hist,
    float* __restrict__ hsum3)
{
    const int bc = blockIdx.x;
    const int part = blockIdx.y;
    const int tid = threadIdx.x;
    const float* base = hpart + (size_t)bc * HSP * 4096;
    float lsum = 0.f;
#pragma unroll
    for (int t = 0; t < 4; ++t) {
        int idx = part * 1024 + t * 256 + tid;
        int u = idx >> 6, v = idx & 63;
        float s = 0.f;
        for (int sp = 0; sp < HSP; ++sp) s += base[sp * 4096 + idx];
        if (u < HB && v < HB) {
            hist[(size_t)bc * (HB * HB) + u * HB + v] = s;
            lsum += s;
        }
    }
    __shared__ float red[4];
    for (int off = 32; off; off >>= 1) lsum += __shfl_down(lsum, off, 64);
    if ((tid & 63) == 0) red[tid >> 6] = lsum;
    __syncthreads();
    if (tid == 0) atomicAdd(&hsum3[bc], red[0] + red[1] + red[2] + red[3]);
}

// ---------------------------------------------------------------------------
// conv1 implicit-GEMM MFMA, NHWC output, M-tile 64 (r15, verified).
// ---------------------------------------------------------------------------
__global__ __launch_bounds__(256) void conv1_mfma(
    const float* __restrict__ hist, const float* __restrict__ hsum3,
    const _Float16* __restrict__ w1h, const float* __restrict__ bias,
    _Float16* __restrict__ out)
{
    const int b    = blockIdx.x;
    const int m0   = blockIdx.y * 64;
    const int tid  = threadIdx.x;
    const int wv   = tid >> 6;
    const int lane = tid & 63;
    const int quad = lane >> 4;
    const int mr   = lane & 15;

    __shared__ __align__(16) _Float16 A_lds[64 * 96];

    const float sc = 1.f / (hsum3[b * 3] + hsum3[b * 3 + 1] + hsum3[b * 3 + 2] + 1e-6f);
    const float* inb = hist + (size_t)b * 3 * 3721;

    for (int slot = tid; slot < 768; slot += 256) {
        int m  = slot & 63;
        int kg = slot >> 6;
        int mg = m0 + m;
        bool mok = (mg < 841);
        int oh = mok ? mg / 29 : 0;
        int ow = mok ? mg % 29 : 0;
        const float* pbase = inb + (oh * 2) * 61 + (ow * 2);
        f16x8 av;
#pragma unroll
        for (int j = 0; j < 8; ++j) {
            int k = kg * 8 + j;
            float x = 0.f;
            if (mok && k < 75) {
                int ci = k / 25, r = k % 25;
                int kh = r / 5, kw = r % 5;
                x = pbase[ci * 3721 + kh * 61 + kw] * sc;
            }
            av[j] = (_Float16)x;
        }
        *(f16x8*)&A_lds[(kg * 64 + m) * 8] = av;
    }
    __syncthreads();

    f16x8 wf[3][2];
#pragma unroll
    for (int ks = 0; ks < 3; ++ks)
#pragma unroll
        for (int nt = 0; nt < 2; ++nt) {
            int co = (wv * 2 + nt) * 16 + mr;
            wf[ks][nt] = *(const f16x8*)&w1h[co * 96 + ks * 32 + quad * 8];
        }

    f32x4 acc[4][2];
#pragma unroll
    for (int mt = 0; mt < 4; ++mt)
#pragma unroll
        for (int nt = 0; nt < 2; ++nt) acc[mt][nt] = (f32x4){0.f, 0.f, 0.f, 0.f};

#pragma unroll
    for (int ks = 0; ks < 3; ++ks)
#pragma unroll
        for (int mt = 0; mt < 4; ++mt) {
            f16x8 bv = *(const f16x8*)&A_lds[((ks * 4 + quad) * 64 + mt * 16 + mr) * 8];
#pragma unroll
            for (int nt = 0; nt < 2; ++nt)
                acc[mt][nt] = __builtin_amdgcn_mfma_f32_16x16x32_f16(bv, wf[ks][nt], acc[mt][nt], 0, 0, 0);
        }

#pragma unroll
    for (int mt = 0; mt < 4; ++mt) {
#pragma unroll
        for (int r = 0; r < 4; ++r) {
            int sp = m0 + mt * 16 + quad * 4 + r;
            if (sp >= 841) continue;
#pragma unroll
            for (int nt = 0; nt < 2; ++nt) {
                int co = (wv * 2 + nt) * 16 + mr;
                float y = acc[mt][nt][r] + bias[co];
                out[((size_t)b * 841 + sp) * 128 + co] = (_Float16)fmaxf(y, 0.f);
            }
        }
    }
}

// ---------------------------------------------------------------------------
// conv2/conv3 implicit-GEMM MFMA, NHWC in/out (r15, verified).
// ---------------------------------------------------------------------------
template<int CIN, int COUT, int Kk, int S, int IN, int OUT,
         int NPB, int KSPL, int KCH>
__global__ __launch_bounds__(256) void conv_mfma(
    const _Float16* __restrict__ in_h,
    const _Float16* __restrict__ w_h,
    float* __restrict__ out)             // [KSPL][B][OSZ][COUT]
{
    constexpr int KK   = Kk * Kk;
    constexpr int OSZ  = OUT * OUT;
    constexpr int MT   = (OSZ + 15) / 16;
    constexpr int MP   = MT * 16;
    constexpr int KTOT = CIN * KK;
    constexpr int KC   = KTOT / KSPL;
    constexpr int NCHUNK = KC / KCH;
    constexpr int NT   = NPB / 64;
    constexpr int KSN  = KCH / 32;
    constexpr int SLOTS = MP * (KCH / 8);

    const int b   = blockIdx.x;
    const int co0 = blockIdx.y * NPB;
    const int k00 = blockIdx.z * KC;
    const int tid  = threadIdx.x;
    const int wv   = tid >> 6;
    const int lane = tid & 63;
    const int quad = lane >> 4;
    const int mr   = lane & 15;

    __shared__ __align__(16) _Float16 A_lds[MP * KCH];

    const _Float16* inb = in_h + (size_t)b * (IN * IN) * CIN;
    float* outp = out + (size_t)blockIdx.z * gridDim.x * OSZ * COUT;

    f32x4 acc[MT][NT];
#pragma unroll
    for (int mt = 0; mt < MT; ++mt)
#pragma unroll
        for (int nt = 0; nt < NT; ++nt) acc[mt][nt] = (f32x4){0.f, 0.f, 0.f, 0.f};

    for (int ch = 0; ch < NCHUNK; ++ch) {
        const int k0 = k00 + ch * KCH;
        __syncthreads();
        for (int slot = tid; slot < SLOTS; slot += 256) {
            int m  = slot % MP;
            int kg = slot / MP;
            bool mok = (m < OSZ);
            int oh = mok ? m / OUT : 0;
            int ow = mok ? m % OUT : 0;
            int kbase = k0 + kg * 8;
            int khkw = kbase / CIN;
            int ci0  = kbase % CIN;
            int kh = khkw / Kk, kw = khkw % Kk;
            f16x8 av = (f16x8)(_Float16)0.f;
            if (mok)
                av = *(const f16x8*)&inb[((size_t)((oh * S + kh) * IN + (ow * S + kw))) * CIN + ci0];
            *(f16x8*)&A_lds[(kg * MP + m) * 8] = av;
        }
        __syncthreads();
        f16x8 wf[KSN][NT];
#pragma unroll
        for (int ks = 0; ks < KSN; ++ks)
#pragma unroll
            for (int nt = 0; nt < NT; ++nt) {
                int co = co0 + (wv * NT + nt) * 16 + mr;
                wf[ks][nt] = *(const f16x8*)&w_h[(size_t)co * KTOT + k0 + ks * 32 + quad * 8];
            }
#pragma unroll
        for (int ks = 0; ks < KSN; ++ks) {
#pragma unroll
            for (int mt = 0; mt < MT; ++mt) {
                f16x8 bv = *(const f16x8*)&A_lds[((ks * 4 + quad) * MP + mt * 16 + mr) * 8];
#pragma unroll
                for (int nt = 0; nt < NT; ++nt)
                    acc[mt][nt] = __builtin_amdgcn_mfma_f32_16x16x32_f16(bv, wf[ks][nt], acc[mt][nt], 0, 0, 0);
            }
        }
    }

#pragma unroll
    for (int mt = 0; mt < MT; ++mt) {
#pragma unroll
        for (int r = 0; r < 4; ++r) {
            int sp = mt * 16 + quad * 4 + r;
            if (sp >= OSZ) continue;
#pragma unroll
            for (int nt = 0; nt < NT; ++nt) {
                int co = co0 + (wv * NT + nt) * 16 + mr;
                outp[((size_t)b * OSZ + sp) * COUT + co] = acc[mt][nt][r];
            }
        }
    }
}

// ---------------------------------------------------------------------------
// float4 split-K reduce + bias + ReLU -> f16 (NHWC: co = 4i % cout).
// ---------------------------------------------------------------------------
__global__ __launch_bounds__(256) void reduce_bias_relu_f16(
    const float* __restrict__ p, const float* __restrict__ bias,
    _Float16* __restrict__ out, int cout, int total4, int kspl, int total)
{
    for (int i4 = blockIdx.x * 256 + threadIdx.x; i4 < total4; i4 += gridDim.x * 256) {
        f32x4 s = (f32x4){0.f, 0.f, 0.f, 0.f};
        for (int ks = 0; ks < kspl; ++ks)
            s += *(const f32x4*)&p[(size_t)ks * total + i4 * 4];
        f32x4 bb = *(const f32x4*)&bias[(i4 * 4) % cout];
        f16x4 o;
#pragma unroll
        for (int j = 0; j < 4; ++j) o[j] = (_Float16)fmaxf(s[j] + bb[j], 0.f);
        *(f16x4*)&out[(size_t)i4 * 4] = o;
    }
}

// ---------------------------------------------------------------------------
// fc as split-K MFMA (r14, verified).
// ---------------------------------------------------------------------------
__global__ __launch_bounds__(256) void fc_mfma(
    const _Float16* __restrict__ z, const _Float16* __restrict__ fcw,
    float* __restrict__ out, int NO)
{
    const int tid  = threadIdx.x;
    const int wv   = tid >> 6;
    const int lane = tid & 63;
    const int quad = lane >> 4;
    const int mr   = lane & 15;
    const int kw0  = blockIdx.x * 512 + wv * 128;

    __shared__ float sred[1024];

    f32x4 acc = (f32x4){0.f, 0.f, 0.f, 0.f};
    const bool bok = (mr < NO);
#pragma unroll
    for (int ks = 0; ks < 4; ++ks) {
        int kk = kw0 + ks * 32 + quad * 8;
        f16x8 av = *(const f16x8*)&z[(size_t)mr * 86528 + kk];
        f16x8 bw = (f16x8)(_Float16)0.f;
        if (bok) bw = *(const f16x8*)&fcw[(size_t)mr * 86528 + kk];
        acc = __builtin_amdgcn_mfma_f32_16x16x32_f16(av, bw, acc, 0, 0, 0);
    }
#pragma unroll
    for (int r = 0; r < 4; ++r)
        sred[wv * 256 + (quad * 4 + r) * 16 + mr] = acc[r];
    __syncthreads();
    if (tid < 256) {
        float s = sred[tid] + sred[256 + tid] + sred[512 + tid] + sred[768 + tid];
        int o = tid & 15, b = tid >> 4;
        if (o < NO) atomicAdd(&out[b * NO + o], s);
    }
}

// ---------------------------------------------------------------------------
// ONE weight-prep kernel (r15, verified).
// ---------------------------------------------------------------------------
__global__ __launch_bounds__(256) void prep_weights(
    const float* __restrict__ w1s, const float* __restrict__ w1i,
    const float* __restrict__ w2s, const float* __restrict__ w3s,
    const float* __restrict__ w2i, const float* __restrict__ w3i,
    const float* __restrict__ fcs, const float* __restrict__ fci,
    _Float16* __restrict__ w1h, _Float16* __restrict__ w23,
    _Float16* __restrict__ fch, float* __restrict__ zp)
{
    const int R0 = 384;
    const int R1 = 24576;
    const int N2 = 294912, N3 = 524288;
    const int R2 = 2 * (N2 + N3);
    const int K = 86528;
    const int R3 = 12 * K;
    const int T = R0 + R1 + R2 + R3;
    for (int i = blockIdx.x * 256 + threadIdx.x; i < T; i += gridDim.x * 256) {
        if (i < R0) {
            zp[i] = 0.f;
        } else if (i < R0 + R1) {
            int r0 = i - R0;
            int br = r0 / 12288, r = r0 % 12288;
            int co = r / 96, k = r % 96;
            const float* s = br ? w1i : w1s;
            w1h[r0] = (k < 75) ? (_Float16)s[co * 75 + k] : (_Float16)0.f;
        } else if (i < R0 + R1 + R2) {
            int j = i - R0 - R1;
            int out_idx = j;
            const float* s; int CK, KKn;
            if (j < N2)                { s = w2s; CK = 1152; KKn = 9; }
            else if (j < N2 + N3)      { s = w3s; j -= N2; CK = 1024; KKn = 4; }
            else if (j < 2 * N2 + N3)  { s = w2i; j -= N2 + N3; CK = 1152; KKn = 9; }
            else                       { s = w3i; j -= 2 * N2 + N3; CK = 1024; KKn = 4; }
            int co = j / CK, rem = j % CK;
            int ci = rem % (CK / KKn), khkw = rem / (CK / KKn);
            w23[out_idx] = (_Float16)s[co * CK + ci * KKn + khkw];
        } else {
            int j = i - R0 - R1 - R2;
            int o = j / K, rem = j % K;
            int sp = rem / 512, co = rem % 512;
            const float* s = (o < 9) ? (fcs + o * K) : (fci + (o - 9) * K);
            fch[j] = (_Float16)s[co * 169 + sp];
        }
    }
}

// ---------------------------------------------------------------------------
// m = reshape(|h|,3,3)^T; n = max L1 row norm + 1e-4; msc = m / n.
// ---------------------------------------------------------------------------
__global__ void build_m(const float* __restrict__ h, float* __restrict__ msc)
{
    int b = threadIdx.x;
    if (b < 16) {
        float m[9];
#pragma unroll
        for (int i = 0; i < 3; ++i)
#pragma unroll
            for (int j = 0; j < 3; ++j) m[i * 3 + j] = fabsf(h[b * 9 + j * 3 + i]);
        float n = 0.f;
#pragma unroll
        for (int i = 0; i < 3; ++i) {
            float r = m[i * 3] + m[i * 3 + 1] + m[i * 3 + 2];
            n = fmaxf(n, r);
        }
        n += 1e-4f;
        float inv = 1.f / n;
#pragma unroll
        for (int k = 0; k < 9; ++k) msc[b * 9 + k] = m[k] * inv;
    }
}

// ---------------------------------------------------------------------------
// est[b] = inv(msc[b]) @ |ill[b]|
// ---------------------------------------------------------------------------
__global__ void final_est(const float* __restrict__ msc, const float* __restrict__ ill,
                          float* __restrict__ out)
{
    int bidx = threadIdx.x;
    if (bidx < 16) {
        const float* m = msc + bidx * 9;
        float a = m[0], b = m[1], c = m[2];
        float d = m[3], e = m[4], f = m[5];
        float g = m[6], h = m[7], i = m[8];
        float A = e * i - f * h, B = f * g - d * i, C = d * h - e * g;
        float D = c * h - b * i, E = a * i - c * g, F = b * g - a * h;
        float G = b * f - c * e, H = c * d - a * f, I = a * e - b * d;
        float det = a * A + b * B + c * C;
        float inv_det = 1.f / det;
        float x0 = fabsf(ill[bidx * 3 + 0]);
        float x1 = fabsf(ill[bidx * 3 + 1]);
        float x2 = fabsf(ill[bidx * 3 + 2]);
        out[bidx * 3 + 0] = (A * x0 + D * x1 + G * x2) * inv_det;
        out[bidx * 3 + 1] = (B * x0 + E * x1 + H * x2) * inv_det;
        out[bidx * 3 + 2] = (C * x0 + F * x1 + I * x2) * inv_det;
    }
}

extern "C" void kernel_launch(void* const* d_in, const int* in_sizes, int n_in,
                              void* d_out, int out_size, void* d_ws, size_t ws_size,
                              hipStream_t stream)
{
    (void)in_sizes; (void)n_in; (void)out_size; (void)ws_size;
    const float* image = (const float*)d_in[0];
    const float* su_s  = (const float*)d_in[1];
    const float* sv_s  = (const float*)d_in[2];
    const float* c_s   = (const float*)d_in[3];
    const float* w1_s  = (const float*)d_in[4];
    const float* b1_s  = (const float*)d_in[5];
    const float* w2_s  = (const float*)d_in[6];
    const float* b2_s  = (const float*)d_in[7];
    const float* w3_s  = (const float*)d_in[8];
    const float* b3_s  = (const float*)d_in[9];
    const float* fc_s  = (const float*)d_in[10];
    const float* su_i  = (const float*)d_in[11];
    const float* sv_i  = (const float*)d_in[12];
    const float* c_i   = (const float*)d_in[13];
    const float* w1_i  = (const float*)d_in[14];
    const float* b1_i  = (const float*)d_in[15];
    const float* w2_i  = (const float*)d_in[16];
    const float* b2_i  = (const float*)d_in[17];
    const float* w3_i  = (const float*)d_in[18];
    const float* b3_i  = (const float*)d_in[19];
    const float* fc_i  = (const float*)d_in[20];

    // ---- workspace: cumulative pointer arithmetic ONLY; hpart/p2/p3 union
    float* W      = (float*)d_ws;
    float* hist   = W;                        // 178608 f
    float* hd     = hist + 178608;            // 144 (zeroed in prep)
    float* hd2    = hd + 144;                 // 144
    float* hsum3a = hd2 + 144;                // 48
    float* hsum3b = hsum3a + 48;              // 48
    float* msc    = hsum3b + 48;              // 144
    float* U      = msc + 144;                // union: max(hpart 4128768,
                                              //   p2 9633792, p3 11075584)
    float* hpart  = U;
    float* p2     = U;
    float* p3     = U;
    _Float16* o1h   = (_Float16*)(U + 11075584);
    _Float16* o2h   = o1h   + 1722368;
    _Float16* o3h   = o2h   + 802816;
    _Float16* fch   = o3h   + 1384448;
    _Float16* w2h_s = fch   + 1038336;
    _Float16* w3h_s = w2h_s + 294912;
    _Float16* w2h_i = w3h_s + 524288;
    _Float16* w3h_i = w2h_i + 294912;
    _Float16* w1h_s = w3h_i + 524288;
    _Float16* w1h_i = w1h_s + 12288;

    const int O2_TOT = 16 * 196 * 256;
    const int O3_TOT = 16 * 169 * 512;
    const int FCK = 86528;

    prep_weights<<<1024, 256, 0, stream>>>(w1_s, w1_i, w2_s, w3_s, w2_i, w3_i,
                                           fc_s, fc_i, w1h_s, w2h_s, fch, hd);

    // ================= sensor branch =================
    hist_mfma<<<dim3(48, HSP), 256, 0, stream>>>(image, su_s, sv_s, c_s, nullptr, hpart);
    reduce_hist<<<dim3(48, 4), 256, 0, stream>>>(hpart, hist, hsum3a);
    conv1_mfma<<<dim3(16, 14), 256, 0, stream>>>(hist, hsum3a, w1h_s, b1_s, o1h);
    conv_mfma<128, 256, 3, 2, 29, 14, 128, 12, 96><<<dim3(16, 2, 12), 256, 0, stream>>>(o1h, w2h_s, p2);
    reduce_bias_relu_f16<<<784, 256, 0, stream>>>(p2, b2_s, o2h, 256, O2_TOT / 4, 12, O2_TOT);
    conv_mfma<256, 512, 2, 1, 14, 13, 128, 8, 64><<<dim3(16, 4, 8), 256, 0, stream>>>(o2h, w3h_s, p3);
    reduce_bias_relu_f16<<<1024, 256, 0, stream>>>(p3, b3_s, o3h, 512, O3_TOT / 4, 8, O3_TOT);
    fc_mfma<<<169, 256, 0, stream>>>(o3h, fch, hd, 9);
    build_m<<<1, 64, 0, stream>>>(hd, msc);

    // ================= illuminant branch =================
    hist_mfma<<<dim3(48, HSP), 256, 0, stream>>>(image, su_i, sv_i, c_i, msc, hpart);
    reduce_hist<<<dim3(48, 4), 256, 0, stream>>>(hpart, hist, hsum3b);
    conv1_mfma<<<dim3(16, 14), 256, 0, stream>>>(hist, hsum3b, w1h_i, b1_i, o1h);
    conv_mfma<128, 256, 3, 2, 29, 14, 128, 12, 96><<<dim3(16, 2, 12), 256, 0, stream>>>(o1h, w2h_i, p2);
    reduce_bias_relu_f16<<<784, 256, 0, stream>>>(p2, b2_i, o2h, 256, O2_TOT / 4, 12, O2_TOT);
    conv_mfma<256, 512, 2, 1, 14, 13, 128, 8, 64><<<dim3(16, 4, 8), 256, 0, stream>>>(o2h, w3h_i, p3);
    reduce_bias_relu_f16<<<1024, 256, 0, stream>>>(p3, b3_i, o3h, 512, O3_TOT / 4, 8, O3_TOT);
    fc_mfma<<<169, 256, 0, stream>>>(o3h, fch + 9 * FCK, hd2, 3);
    final_est<<<1, 64, 0, stream>>>(msc, hd2, (float*)d_out);
}